// Round 8
// baseline (187.246 us; speedup 1.0000x reference)
//
#include <hip/hip_runtime.h>

typedef __attribute__((ext_vector_type(8))) short bf16x8;
typedef __attribute__((ext_vector_type(4))) float f32x4;

// ---------------------------------------------------------------------------
// f32 -> bf16 round-to-nearest-even
__device__ __forceinline__ unsigned short f2bf(float x) {
    unsigned u = __float_as_uint(x);
    u += 0x7fffu + ((u >> 16) & 1u);
    return (unsigned short)(u >> 16);
}

// Fused slice + convert + mask-zero for BOTH inputs (one launch).
__global__ void conv_kernel(const float* __restrict__ im, const int* __restrict__ iml,
                            const float* __restrict__ ss, const int* __restrict__ sl,
                            unsigned short* __restrict__ Ad, unsigned short* __restrict__ Bd)
{
    int bid = blockIdx.x;
    const float* src; const int* len; unsigned short* dst; int rawL, adj;
    if (bid < 8192) { src = im; len = iml; dst = Ad; rawL = 65; adj = -1; }
    else { bid -= 8192; src = ss; len = sl; dst = Bd; rawL = 67; adj = -3; }
    int m = bid;
    int c = threadIdx.x << 2;
    int b = m >> 6;
    int i = m & 63;
    int lim = len[b] + adj;
    float4 v;
    if (i < lim) {
        v = *(const float4*)(src + ((size_t)(b * rawL + 1 + i) << 10) + c);
    } else {
        v = make_float4(0.f, 0.f, 0.f, 0.f);
    }
    ushort4 o;
    o.x = f2bf(v.x); o.y = f2bf(v.y); o.z = f2bf(v.z); o.w = f2bf(v.w);
    *(ushort4*)(dst + ((size_t)m << 10) + c) = o;
}

// ---------------------------------------------------------------------------
__device__ __forceinline__ void gload_lds16(const void* g, void* l) {
    __builtin_amdgcn_global_load_lds((const __attribute__((address_space(1))) void*)g,
                                     (__attribute__((address_space(3))) void*)l,
                                     16, 0, 0);
}

// 256x256 tile, BK=64, 8 waves (2M x 4N), per-wave 128x64 output, 16x16x32 MFMA.
// BARRIER-FREE tile interior: one {vmcnt(0); s_barrier} gate per tile (loads
// being waited are a full tile old -> free). Full tile t+1 staged right after
// the gate. Inside the tile: 1-deep fragment pipeline (issue af(q+1) reads
// before MFMA(q); compiler emits counted lgkmcnt) + wave-rotated quadrant
// order (even waves q0..q3, odd waves q2,q3,q0,q1) so LDS and MFMA pipes stay
// concurrently fed instead of CU-wide read/MFMA burst alternation.
// Fused wave-local reduction: aggr[b,t] = sum_j max_i C_cell.
__global__ void __launch_bounds__(512) gemm_aggr_kernel(const unsigned short* __restrict__ A,
                                                        const unsigned short* __restrict__ B,
                                                        float* __restrict__ aggr)
{
    __shared__ __align__(16) unsigned short As[2][2][128 * 64];   // [buf][half] 64 KiB
    __shared__ __align__(16) unsigned short Bs[2][2][128 * 64];   // [buf][half] 64 KiB

    const int tid  = threadIdx.x;
    const int lane = tid & 63;
    const int wid  = tid >> 6;        // 0..7
    const int wr   = wid >> 2;        // 0..1 : 128-row half of BM
    const int wc   = wid & 3;         // 0..3 : 64-col quarter of BN
    const int tm   = blockIdx.y;      // 0..31
    const int tn   = blockIdx.x;      // 0..31

    const int r15 = lane & 15;
    const int g4  = lane >> 4;        // 0..3
    const int swz = r15 & 7;

    // Staging: per half 2 rounds of 64 rows x 64 cols (8 KB = 512 thr x 16 B).
    // LDS dest linear; global source chunk pre-swizzled (both-sides XOR).
    const int srow   = tid >> 3;                  // 0..63
    const int schunk = (tid & 7) ^ (srow & 7);
    const unsigned short* gA_t = A + ((size_t)(tm * 256 + srow) << 10) + schunk * 8;
    const unsigned short* gB_t = B + ((size_t)(tn * 256 + srow) << 10) + schunk * 8;

#define STAGE_A(kt, h, r) gload_lds16(gA_t + (((size_t)((h) * 128 + (r) * 64)) << 10) + (kt) * 64, \
                                      (char*)As[(kt) & 1][h] + (r) * 8192 + tid * 16)
#define STAGE_B(kt, h, r) gload_lds16(gB_t + (((size_t)((h) * 128 + (r) * 64)) << 10) + (kt) * 64, \
                                      (char*)Bs[(kt) & 1][h] + (r) * 8192 + tid * 16)

    f32x4 acc[4][2][4];   // [32-row quadrant][mi][ni]
#pragma unroll
    for (int p = 0; p < 4; ++p)
#pragma unroll
        for (int mi = 0; mi < 2; ++mi)
#pragma unroll
            for (int ni = 0; ni < 4; ++ni)
                acc[p][mi][ni] = (f32x4){0.f, 0.f, 0.f, 0.f};

    // Prologue: stage tile 0 fully (8 gloads).
    STAGE_A(0, 0, 0); STAGE_A(0, 0, 1); STAGE_A(0, 1, 0); STAGE_A(0, 1, 1);
    STAGE_B(0, 0, 0); STAGE_B(0, 0, 1); STAGE_B(0, 1, 0); STAGE_B(0, 1, 1);

    const int BrowO = ((wc & 1) * 64 + r15) * 128;   // byte row base within B half
    const int ArowO = r15 * 128;                     // + (q*32 + mi*16)*128
    const int ch0 = (g4 ^ swz) * 16;
    const int ch1 = ((4 + g4) ^ swz) * 16;

    bf16x8 bg[4][2];

#define LOAD_AQ(AF, Ab, Q)                                                  \
    _Pragma("unroll")                                                       \
    for (int mi = 0; mi < 2; ++mi) {                                        \
        const int o_ = ArowO + ((Q) * 32 + mi * 16) * 128;                  \
        AF[mi][0] = *(const bf16x8*)((Ab) + o_ + ch0);                      \
        AF[mi][1] = *(const bf16x8*)((Ab) + o_ + ch1);                      \
    }

#define MFMA_Q(Q, AF)                                                      \
    __builtin_amdgcn_s_setprio(1);                                          \
    _Pragma("unroll")                                                       \
    for (int mi = 0; mi < 2; ++mi)                                          \
      _Pragma("unroll")                                                     \
      for (int ni = 0; ni < 4; ++ni) {                                      \
        acc[Q][mi][ni] = __builtin_amdgcn_mfma_f32_16x16x32_bf16(           \
            AF[mi][0], bg[ni][0], acc[Q][mi][ni], 0, 0, 0);                 \
        acc[Q][mi][ni] = __builtin_amdgcn_mfma_f32_16x16x32_bf16(           \
            AF[mi][1], bg[ni][1], acc[Q][mi][ni], 0, 0, 0);                 \
      }                                                                     \
    __builtin_amdgcn_s_setprio(0);

#define SB __builtin_amdgcn_sched_barrier(0)

// 1-deep pipelined quadrant sequence: af(next) issued before MFMA(cur).
#define QPIPE(Q0, Q1, Q2, Q3)                                               \
    LOAD_AQ(afA, Ab, Q0) SB;                                                \
    LOAD_AQ(afB, Ab, Q1) SB;                                                \
    MFMA_Q(Q0, afA) SB;                                                     \
    LOAD_AQ(afA, Ab, Q2) SB;                                                \
    MFMA_Q(Q1, afB) SB;                                                     \
    LOAD_AQ(afB, Ab, Q3) SB;                                                \
    MFMA_Q(Q2, afA) SB;                                                     \
    MFMA_Q(Q3, afB)

    for (int kt = 0; kt < 16; ++kt) {
        const char* Ab = (const char*)As[kt & 1][wr];
        const char* Bb = (const char*)Bs[kt & 1][wc >> 1];
        bf16x8 afA[2][2], afB[2][2];

        // ---- per-tile gate: own loads done, then all-waves sync ----
        asm volatile("s_waitcnt vmcnt(0)" ::: "memory");   // tile-kt loads (issued @ kt-1) landed
        __builtin_amdgcn_s_barrier();                      // + all waves' loads, + t-1 reads fenced
        SB;
        if (kt < 15) {
            STAGE_A(kt + 1, 0, 0); STAGE_A(kt + 1, 0, 1);
            STAGE_A(kt + 1, 1, 0); STAGE_A(kt + 1, 1, 1);
            STAGE_B(kt + 1, 0, 0); STAGE_B(kt + 1, 0, 1);
            STAGE_B(kt + 1, 1, 0); STAGE_B(kt + 1, 1, 1);
        }
        SB;
        // B fragments for the whole tile (8 reads)
#pragma unroll
        for (int ni = 0; ni < 4; ++ni) {
            bg[ni][0] = *(const bf16x8*)(Bb + BrowO + ni * 2048 + ch0);
            bg[ni][1] = *(const bf16x8*)(Bb + BrowO + ni * 2048 + ch1);
        }
        SB;
        // barrier-free interior, wave-rotated quadrant order
        if ((wid & 1) == 0) {
            QPIPE(0, 1, 2, 3);
        } else {
            QPIPE(2, 3, 0, 1);
        }
    }
#undef STAGE_A
#undef STAGE_B
#undef LOAD_AQ
#undef MFMA_Q
#undef QPIPE
#undef SB

    // Fused reduction per 64x64 (b,t) cell. C/D: col=lane&15, row=(lane>>4)*4+reg.
#pragma unroll
    for (int h = 0; h < 2; ++h) {
        float cm[4];
#pragma unroll
        for (int ni = 0; ni < 4; ++ni) {
            float m = acc[h * 2][0][ni][0];
#pragma unroll
            for (int pp = 0; pp < 2; ++pp)
#pragma unroll
                for (int mi = 0; mi < 2; ++mi)
#pragma unroll
                    for (int r = 0; r < 4; ++r)
                        m = fmaxf(m, acc[h * 2 + pp][mi][ni][r]);
            m = fmaxf(m, __shfl_xor(m, 16));
            m = fmaxf(m, __shfl_xor(m, 32));
            cm[ni] = m;
        }
        float s = cm[0] + cm[1] + cm[2] + cm[3];
        s += __shfl_xor(s, 1);
        s += __shfl_xor(s, 2);
        s += __shfl_xor(s, 4);
        s += __shfl_xor(s, 8);
        if (lane == 0) {
            int b = tm * 4 + wr * 2 + h;
            int t = tn * 4 + wc;
            aggr[b * 128 + t] = s;
        }
    }
}

// ---------------------------------------------------------------------------
__global__ void loss_kernel(const float* __restrict__ aggr, float* __restrict__ out)
{
    __shared__ float red[128];
    const int x = threadIdx.x;
    const float diag = aggr[x * 128 + x];
    float mrow = 0.f, mcol = 0.f;
    for (int y = 0; y < 128; ++y) {
        if (y == x) continue;
        float a_xy = aggr[x * 128 + y];
        float a_yx = aggr[y * 128 + x];
        mrow = fmaxf(mrow, 0.2f + a_xy - diag);
        mcol = fmaxf(mcol, 0.2f + a_yx - diag);
    }
    red[x] = mrow + mcol;
    __syncthreads();
    if (x == 0) {
        float s = 0.f;
        for (int i = 0; i < 128; ++i) s += red[i];
        *out = s;
    }
}

// ---------------------------------------------------------------------------
extern "C" void kernel_launch(void* const* d_in, const int* in_sizes, int n_in,
                              void* d_out, int out_size, void* d_ws, size_t ws_size,
                              hipStream_t stream)
{
    const float* im_set = (const float*)d_in[0];
    const float* s_seq  = (const float*)d_in[1];
    const int*   im_len = (const int*)d_in[2];
    const int*   s_len  = (const int*)d_in[3];
    float* out = (float*)d_out;

    unsigned short* Abf = (unsigned short*)d_ws;                           // 16 MiB
    unsigned short* Bbf = (unsigned short*)((char*)d_ws + (16u << 20));    // 16 MiB
    float*          agg = (float*)((char*)d_ws + (32u << 20));             // 64 KiB

    conv_kernel<<<16384, 256, 0, stream>>>(im_set, im_len, s_seq, s_len, Abf, Bbf);

    gemm_aggr_kernel<<<dim3(32, 32), 512, 0, stream>>>(Abf, Bbf, agg);

    loss_kernel<<<1, 128, 0, stream>>>(agg, out);
}

// Round 9
// 155.673 us; speedup vs baseline: 1.2028x; 1.2028x over previous
//
#include <hip/hip_runtime.h>

typedef __attribute__((ext_vector_type(8))) short bf16x8;
typedef __attribute__((ext_vector_type(16))) float f32x16;

// ---------------------------------------------------------------------------
// f32 -> bf16 round-to-nearest-even
__device__ __forceinline__ unsigned short f2bf(float x) {
    unsigned u = __float_as_uint(x);
    u += 0x7fffu + ((u >> 16) & 1u);
    return (unsigned short)(u >> 16);
}

// Fused slice + convert + mask-zero for BOTH inputs (one launch).
__global__ void conv_kernel(const float* __restrict__ im, const int* __restrict__ iml,
                            const float* __restrict__ ss, const int* __restrict__ sl,
                            unsigned short* __restrict__ Ad, unsigned short* __restrict__ Bd)
{
    int bid = blockIdx.x;
    const float* src; const int* len; unsigned short* dst; int rawL, adj;
    if (bid < 8192) { src = im; len = iml; dst = Ad; rawL = 65; adj = -1; }
    else { bid -= 8192; src = ss; len = sl; dst = Bd; rawL = 67; adj = -3; }
    int m = bid;
    int c = threadIdx.x << 2;
    int b = m >> 6;
    int i = m & 63;
    int lim = len[b] + adj;
    float4 v;
    if (i < lim) {
        v = *(const float4*)(src + ((size_t)(b * rawL + 1 + i) << 10) + c);
    } else {
        v = make_float4(0.f, 0.f, 0.f, 0.f);
    }
    ushort4 o;
    o.x = f2bf(v.x); o.y = f2bf(v.y); o.z = f2bf(v.z); o.w = f2bf(v.w);
    *(ushort4*)(dst + ((size_t)m << 10) + c) = o;
}

// ---------------------------------------------------------------------------
__device__ __forceinline__ void gload_lds16(const void* g, void* l) {
    __builtin_amdgcn_global_load_lds((const __attribute__((address_space(1))) void*)g,
                                     (__attribute__((address_space(3))) void*)l,
                                     16, 0, 0);
}

// 256x256 tile, BK=64, 8 waves (2M x 4N), per-wave 128x64 output.
// MFMA shape: 32x32x16 bf16 (higher ceiling, half the instruction count).
// Round-6 schedule: 2 gated half-tiles/tile; staging {B01,B23 | A02,A13};
// gates vmcnt(2)@h0, vmcnt(4)@h1, tail vmcnt(0). XOR-16B LDS swizzle
// (pre-swizzled global source + swizzled read), zero-conflict.
// Fragment layouts (gfx950): A row=lane&31, k=(lane>>5)*8+j;
// C/D col=lane&31, row=(reg&3)+8*(reg>>2)+4*(lane>>5)  [m74/m101].
// Fused wave-local reduction: aggr[b,t] = sum_j max_i C_cell.
__global__ void __launch_bounds__(512) gemm_aggr_kernel(const unsigned short* __restrict__ A,
                                                        const unsigned short* __restrict__ B,
                                                        float* __restrict__ aggr)
{
    __shared__ __align__(16) unsigned short As[2][2][128 * 64];   // [buf][half] 64 KiB
    __shared__ __align__(16) unsigned short Bs[2][2][128 * 64];   // [buf][half] 64 KiB

    const int tid  = threadIdx.x;
    const int lane = tid & 63;
    const int wid  = tid >> 6;        // 0..7
    const int wr   = wid >> 2;        // 0..1 : 128-row half of BM
    const int wc   = wid & 3;         // 0..3 : 64-col quarter of BN
    const int tm   = blockIdx.y;      // 0..31
    const int tn   = blockIdx.x;      // 0..31

    const int r31 = lane & 31;
    const int g2  = lane >> 5;        // 0..1
    const int swz = r31 & 7;

    // Staging: per half 2 rounds of 64 rows x 64 cols (8 KB = 512 thr x 16 B).
    // LDS dest linear; global source granule pre-swizzled (both-sides XOR).
    const int srow   = tid >> 3;                  // 0..63
    const int schunk = (tid & 7) ^ (srow & 7);
    const unsigned short* gA_t = A + ((size_t)(tm * 256 + srow) << 10) + schunk * 8;
    const unsigned short* gB_t = B + ((size_t)(tn * 256 + srow) << 10) + schunk * 8;

#define STAGE_A(kt, h, r) gload_lds16(gA_t + (((size_t)((h) * 128 + (r) * 64)) << 10) + (kt) * 64, \
                                      (char*)As[(kt) & 1][h] + (r) * 8192 + tid * 16)
#define STAGE_B(kt, h, r) gload_lds16(gB_t + (((size_t)((h) * 128 + (r) * 64)) << 10) + (kt) * 64, \
                                      (char*)Bs[(kt) & 1][h] + (r) * 8192 + tid * 16)

    f32x16 acc[4][2];   // [32-row block mi][32-col block ni]
#pragma unroll
    for (int mi = 0; mi < 4; ++mi)
#pragma unroll
        for (int ni = 0; ni < 2; ++ni)
#pragma unroll
            for (int r = 0; r < 16; ++r)
                acc[mi][ni][r] = 0.f;

    // Prologue: tile 0 in steady-state order [B00 B01 B10 B11 A00 A10 A01 A11].
    STAGE_B(0, 0, 0); STAGE_B(0, 0, 1); STAGE_B(0, 1, 0); STAGE_B(0, 1, 1);
    STAGE_A(0, 0, 0); STAGE_A(0, 1, 0); STAGE_A(0, 0, 1); STAGE_A(0, 1, 1);

    // data granule for k-step ks is (ks*2 + g2); stored at position g^(row&7)
    const int ch[4] = { ((0 + g2) ^ swz) * 16, ((2 + g2) ^ swz) * 16,
                        ((4 + g2) ^ swz) * 16, ((6 + g2) ^ swz) * 16 };
    const int ArBase = r31 * 128;                       // + mi*4096
    const int BrBase = ((wc & 1) * 64 + r31) * 128;     // + ni*4096

    bf16x8 bg[2][4];

#define LOAD_AMI(AF, MI)                                                    \
    _Pragma("unroll")                                                       \
    for (int ks = 0; ks < 4; ++ks)                                          \
        AF[ks] = *(const bf16x8*)(Ab + ArBase + (MI) * 4096 + ch[ks]);

#define MFMA_MI(MI, AF)                                                     \
    __builtin_amdgcn_s_setprio(1);                                          \
    _Pragma("unroll")                                                       \
    for (int ks = 0; ks < 4; ++ks)                                          \
      _Pragma("unroll")                                                     \
      for (int ni = 0; ni < 2; ++ni)                                        \
        acc[MI][ni] = __builtin_amdgcn_mfma_f32_32x32x16_bf16(              \
            AF[ks], bg[ni][ks], acc[MI][ni], 0, 0, 0);                      \
    __builtin_amdgcn_s_setprio(0);

#define SB __builtin_amdgcn_sched_barrier(0)

#pragma unroll 2
    for (int kt = 0; kt < 16; ++kt) {
        const char* Ab = (const char*)As[kt & 1][wr];
        const char* Bb = (const char*)Bs[kt & 1][wc >> 1];
        bf16x8 af0[4], af1[4];

        // ======== half-tile 0 : mi 0,1 ========
        // gate: B(kt) all 4 rounds + A(kt) r0 of both halves landed (6 oldest)
        asm volatile("s_waitcnt vmcnt(2)" ::: "memory");
        __builtin_amdgcn_s_barrier();
        SB;
        // reads MFMA(mi=0) depends on: bg (8) + af0 (4)
#pragma unroll
        for (int ks = 0; ks < 4; ++ks) {
            bg[0][ks] = *(const bf16x8*)(Bb + BrBase + ch[ks]);
            bg[1][ks] = *(const bf16x8*)(Bb + BrBase + 4096 + ch[ks]);
        }
        LOAD_AMI(af0, 0)
        SB;
        LOAD_AMI(af1, 1)
        SB;
        if (kt < 15) { STAGE_B(kt + 1, 0, 0); STAGE_B(kt + 1, 0, 1); }
        SB;
        MFMA_MI(0, af0)
        if (kt < 15) { STAGE_B(kt + 1, 1, 0); STAGE_B(kt + 1, 1, 1); }
        SB;
        MFMA_MI(1, af1)

        // ======== half-tile 1 : mi 2,3 ========
        // gate: A(kt) r1 of both halves landed (newest 4 = B(kt+1))
        if (kt < 15) { asm volatile("s_waitcnt vmcnt(4)" ::: "memory"); }
        else         { asm volatile("s_waitcnt vmcnt(0)" ::: "memory"); }
        __builtin_amdgcn_s_barrier();
        SB;
        LOAD_AMI(af0, 2)
        SB;
        LOAD_AMI(af1, 3)
        SB;
        if (kt < 15) { STAGE_A(kt + 1, 0, 0); STAGE_A(kt + 1, 1, 0); }
        SB;
        MFMA_MI(2, af0)
        if (kt < 15) { STAGE_A(kt + 1, 0, 1); STAGE_A(kt + 1, 1, 1); }
        SB;
        MFMA_MI(3, af1)
    }
#undef STAGE_A
#undef STAGE_B
#undef LOAD_AMI
#undef MFMA_MI
#undef SB

    // Fused reduction per 64x64 (b,t) cell.
    // C/D layout: col = lane&31, row = (reg&3) + 8*(reg>>2) + 4*(lane>>5).
    // Cell h covers mi {2h, 2h+1} (rows) x ni {0,1} (cols).
#pragma unroll
    for (int h = 0; h < 2; ++h) {
        float cm[2];
#pragma unroll
        for (int ni = 0; ni < 2; ++ni) {
            float m = acc[h * 2][ni][0];
#pragma unroll
            for (int dm = 0; dm < 2; ++dm)
#pragma unroll
                for (int r = 0; r < 16; ++r)
                    m = fmaxf(m, acc[h * 2 + dm][ni][r]);
            m = fmaxf(m, __shfl_xor(m, 32));   // other 16 rows of each 32-row tile
            cm[ni] = m;                        // col max, replicated over lane>>5
        }
        float s = cm[0] + cm[1];
        s += __shfl_xor(s, 1);
        s += __shfl_xor(s, 2);
        s += __shfl_xor(s, 4);
        s += __shfl_xor(s, 8);
        s += __shfl_xor(s, 16);
        if (lane == 0) {
            int b = tm * 4 + wr * 2 + h;
            int t = tn * 4 + wc;
            aggr[b * 128 + t] = s;
        }
    }
}

// ---------------------------------------------------------------------------
__global__ void loss_kernel(const float* __restrict__ aggr, float* __restrict__ out)
{
    __shared__ float red[128];
    const int x = threadIdx.x;
    const float diag = aggr[x * 128 + x];
    float mrow = 0.f, mcol = 0.f;
    for (int y = 0; y < 128; ++y) {
        if (y == x) continue;
        float a_xy = aggr[x * 128 + y];
        float a_yx = aggr[y * 128 + x];
        mrow = fmaxf(mrow, 0.2f + a_xy - diag);
        mcol = fmaxf(mcol, 0.2f + a_yx - diag);
    }
    red[x] = mrow + mcol;
    __syncthreads();
    if (x == 0) {
        float s = 0.f;
        for (int i = 0; i < 128; ++i) s += red[i];
        *out = s;
    }
}

// ---------------------------------------------------------------------------
extern "C" void kernel_launch(void* const* d_in, const int* in_sizes, int n_in,
                              void* d_out, int out_size, void* d_ws, size_t ws_size,
                              hipStream_t stream)
{
    const float* im_set = (const float*)d_in[0];
    const float* s_seq  = (const float*)d_in[1];
    const int*   im_len = (const int*)d_in[2];
    const int*   s_len  = (const int*)d_in[3];
    float* out = (float*)d_out;

    unsigned short* Abf = (unsigned short*)d_ws;                           // 16 MiB
    unsigned short* Bbf = (unsigned short*)((char*)d_ws + (16u << 20));    // 16 MiB
    float*          agg = (float*)((char*)d_ws + (32u << 20));             // 64 KiB

    conv_kernel<<<16384, 256, 0, stream>>>(im_set, im_len, s_seq, s_len, Abf, Bbf);

    gemm_aggr_kernel<<<dim3(32, 32), 512, 0, stream>>>(Abf, Bbf, agg);

    loss_kernel<<<1, 128, 0, stream>>>(agg, out);
}

// Round 10
// 105.971 us; speedup vs baseline: 1.7670x; 1.4690x over previous
//
#include <hip/hip_runtime.h>
#include <hip/hip_fp8.h>

typedef __attribute__((ext_vector_type(8))) int   i32x8;
typedef __attribute__((ext_vector_type(16))) float f32x16;

// ---------------------------------------------------------------------------
// Fused slice + convert(f32 -> fp8 e4m3 OCP) + mask-zero for BOTH inputs.
// blocks 0..8191 -> im_set[:,1:,:] rows >= im_len-1 zeroed -> Ad
// blocks 8192..16383 -> s_seq[:,1:-2,:] rows >= s_len-3 zeroed -> Bd
__global__ void conv_kernel(const float* __restrict__ im, const int* __restrict__ iml,
                            const float* __restrict__ ss, const int* __restrict__ sl,
                            unsigned char* __restrict__ Ad, unsigned char* __restrict__ Bd)
{
    int bid = blockIdx.x;
    const float* src; const int* len; unsigned char* dst; int rawL, adj;
    if (bid < 8192) { src = im; len = iml; dst = Ad; rawL = 65; adj = -1; }
    else { bid -= 8192; src = ss; len = sl; dst = Bd; rawL = 67; adj = -3; }
    int m = bid;
    int c = threadIdx.x << 2;
    int b = m >> 6;
    int i = m & 63;
    int lim = len[b] + adj;
    float4 v;
    if (i < lim) {
        v = *(const float4*)(src + ((size_t)(b * rawL + 1 + i) << 10) + c);
    } else {
        v = make_float4(0.f, 0.f, 0.f, 0.f);
    }
    uchar4 o;
    o.x = __hip_cvt_float_to_fp8(v.x, __HIP_SATFINITE, __HIP_E4M3);
    o.y = __hip_cvt_float_to_fp8(v.y, __HIP_SATFINITE, __HIP_E4M3);
    o.z = __hip_cvt_float_to_fp8(v.z, __HIP_SATFINITE, __HIP_E4M3);
    o.w = __hip_cvt_float_to_fp8(v.w, __HIP_SATFINITE, __HIP_E4M3);
    *(uchar4*)(dst + ((size_t)m << 10) + c) = o;
}

// ---------------------------------------------------------------------------
__device__ __forceinline__ void gload_lds16(const void* g, void* l) {
    __builtin_amdgcn_global_load_lds((const __attribute__((address_space(1))) void*)g,
                                     (__attribute__((address_space(3))) void*)l,
                                     16, 0, 0);
}

// Read a 32-byte fp8 operand fragment as two XOR-swizzled b128 granules.
// Data granule e sits at LDS position (e ^ swz); e even -> partner at o0^16.
__device__ __forceinline__ i32x8 rd32(const char* base, int o0) {
    int4 a = *(const int4*)(base + o0);
    int4 b = *(const int4*)(base + (o0 ^ 16));
    i32x8 r;
    r[0] = a.x; r[1] = a.y; r[2] = a.z; r[3] = a.w;
    r[4] = b.x; r[5] = b.y; r[6] = b.z; r[7] = b.w;
    return r;
}

// 256x256 tile, BK=128 (fp8 bytes = 128B rows), 8 waves (2M x 4N), per-wave
// 128x64 output, MFMA: mfma_scale_f32_32x32x64_f8f6f4, fmt0=e4m3, scale=1.0
// (E8M0 127). Round-6-verified schedule: 2 gated half-tiles/tile, staging
// order {B00,B01,B10,B11 | A00,A10,A01,A11}, gates vmcnt(2)@h0, vmcnt(4)@h1,
// tail vmcnt(0). XOR-16B swizzle (pre-swizzled global source + swizzled read).
// C/D layout (r9-verified): col=lane&31, row=(reg&3)+8*(reg>>2)+4*(lane>>5).
// Fused wave-local reduction: aggr[b,t] = sum_j max_i C_cell.
__global__ void __launch_bounds__(512) gemm_aggr_kernel(const unsigned char* __restrict__ A,
                                                        const unsigned char* __restrict__ B,
                                                        float* __restrict__ aggr)
{
    __shared__ __align__(16) char As[2][32768];   // 2 x 32 KiB (256 rows x 128 B)
    __shared__ __align__(16) char Bs[2][32768];

    const int tid  = threadIdx.x;
    const int lane = tid & 63;
    const int wid  = tid >> 6;        // 0..7
    const int wr   = wid >> 2;        // 0..1 : 128-row half of BM
    const int wc   = wid & 3;         // 0..3 : 64-col quarter of BN
    const int tm   = blockIdx.y;      // 0..31
    const int tn   = blockIdx.x;      // 0..31

    const int r31 = lane & 31;
    const int g2  = lane >> 5;        // 0..1
    const int swz = r31 & 7;

    // Staging: round = 64 rows x 128 B = 8 KB = 512 thr x 16 B.
    // LDS dest linear; global source granule pre-swizzled (both-sides XOR).
    const int srow   = tid >> 3;                  // 0..63
    const int schunk = (tid & 7) ^ (srow & 7);
    const unsigned char* gA_t = A + ((size_t)(tm * 256 + srow) << 10) + schunk * 16;
    const unsigned char* gB_t = B + ((size_t)(tn * 256 + srow) << 10) + schunk * 16;

#define STAGE_A(kt, h, r) gload_lds16(gA_t + (((size_t)((h) * 128 + (r) * 64)) << 10) + (kt) * 128, \
                                      As[(kt) & 1] + ((h) * 2 + (r)) * 8192 + tid * 16)
#define STAGE_B(kt, h, r) gload_lds16(gB_t + (((size_t)((h) * 128 + (r) * 64)) << 10) + (kt) * 128, \
                                      Bs[(kt) & 1] + ((h) * 2 + (r)) * 8192 + tid * 16)

    f32x16 acc[4][2];   // [32-row block mi][32-col block ni]
#pragma unroll
    for (int mi = 0; mi < 4; ++mi)
#pragma unroll
        for (int ni = 0; ni < 2; ++ni)
#pragma unroll
            for (int r = 0; r < 16; ++r)
                acc[mi][ni][r] = 0.f;

    // Prologue: tile 0 in steady-state order.
    STAGE_B(0, 0, 0); STAGE_B(0, 0, 1); STAGE_B(0, 1, 0); STAGE_B(0, 1, 1);
    STAGE_A(0, 0, 0); STAGE_A(0, 1, 0); STAGE_A(0, 0, 1); STAGE_A(0, 1, 1);

    // k-chunk granule bases: kk selects 64-byte half, g2 selects 32-byte sub.
    const int o0k[2] = { ((g2 * 2) ^ swz) * 16, ((4 + g2 * 2) ^ swz) * 16 };

    i32x8 bg[2][2];   // [ni][kk]

#define LOAD_AMI(AF, Ab, MI)                                                \
    _Pragma("unroll")                                                       \
    for (int kk = 0; kk < 2; ++kk)                                          \
        AF[kk] = rd32((Ab) + ((MI) * 32 + r31) * 128, o0k[kk]);

#define MFMA_MI(MI, AF)                                                     \
    __builtin_amdgcn_s_setprio(1);                                          \
    _Pragma("unroll")                                                       \
    for (int kk = 0; kk < 2; ++kk)                                          \
      _Pragma("unroll")                                                     \
      for (int ni = 0; ni < 2; ++ni)                                        \
        acc[MI][ni] = __builtin_amdgcn_mfma_scale_f32_32x32x64_f8f6f4(      \
            AF[kk], bg[ni][kk], acc[MI][ni], 0, 0, 0, 127, 0, 127);         \
    __builtin_amdgcn_s_setprio(0);

#define SB __builtin_amdgcn_sched_barrier(0)

#pragma unroll 2
    for (int kt = 0; kt < 8; ++kt) {
        const char* Ab = As[kt & 1] + wr * 16384;
        const char* Bb = Bs[kt & 1] + (wc >> 1) * 16384;
        i32x8 af0[2], af1[2];

        // ======== half-tile 0 : mi 0,1 ========
        // gate: B(kt) all rounds + A(kt) (h,0) both halves landed (6 oldest)
        asm volatile("s_waitcnt vmcnt(2)" ::: "memory");
        __builtin_amdgcn_s_barrier();
        SB;
#pragma unroll
        for (int ni = 0; ni < 2; ++ni)
#pragma unroll
            for (int kk = 0; kk < 2; ++kk)
                bg[ni][kk] = rd32(Bb + ((wc & 1) * 64 + ni * 32 + r31) * 128, o0k[kk]);
        LOAD_AMI(af0, Ab, 0)
        SB;
        LOAD_AMI(af1, Ab, 1)
        SB;
        if (kt < 7) { STAGE_B(kt + 1, 0, 0); STAGE_B(kt + 1, 0, 1); }
        SB;
        MFMA_MI(0, af0)
        if (kt < 7) { STAGE_B(kt + 1, 1, 0); STAGE_B(kt + 1, 1, 1); }
        SB;
        MFMA_MI(1, af1)

        // ======== half-tile 1 : mi 2,3 ========
        // gate: A(kt) (h,1) both halves landed (newest 4 = B(kt+1))
        if (kt < 7) { asm volatile("s_waitcnt vmcnt(4)" ::: "memory"); }
        else        { asm volatile("s_waitcnt vmcnt(0)" ::: "memory"); }
        __builtin_amdgcn_s_barrier();
        SB;
        LOAD_AMI(af0, Ab, 2)
        SB;
        LOAD_AMI(af1, Ab, 3)
        SB;
        if (kt < 7) { STAGE_A(kt + 1, 0, 0); STAGE_A(kt + 1, 1, 0); }
        SB;
        MFMA_MI(2, af0)
        if (kt < 7) { STAGE_A(kt + 1, 0, 1); STAGE_A(kt + 1, 1, 1); }
        SB;
        MFMA_MI(3, af1)
    }
#undef STAGE_A
#undef STAGE_B
#undef LOAD_AMI
#undef MFMA_MI
#undef SB

    // Fused reduction per 64x64 (b,t) cell (r9-verified layout).
    // C/D: col = lane&31, row = (reg&3) + 8*(reg>>2) + 4*(lane>>5).
#pragma unroll
    for (int h = 0; h < 2; ++h) {
        float cm[2];
#pragma unroll
        for (int ni = 0; ni < 2; ++ni) {
            float m = acc[h * 2][ni][0];
#pragma unroll
            for (int dm = 0; dm < 2; ++dm)
#pragma unroll
                for (int r = 0; r < 16; ++r)
                    m = fmaxf(m, acc[h * 2 + dm][ni][r]);
            m = fmaxf(m, __shfl_xor(m, 32));   // other 16 rows of the 32-row tile
            cm[ni] = m;                        // col max, replicated over lane>>5
        }
        float s = cm[0] + cm[1];
        s += __shfl_xor(s, 1);
        s += __shfl_xor(s, 2);
        s += __shfl_xor(s, 4);
        s += __shfl_xor(s, 8);
        s += __shfl_xor(s, 16);
        if (lane == 0) {
            int b = tm * 4 + wr * 2 + h;
            int t = tn * 4 + wc;
            aggr[b * 128 + t] = s;
        }
    }
}

// ---------------------------------------------------------------------------
__global__ void loss_kernel(const float* __restrict__ aggr, float* __restrict__ out)
{
    __shared__ float red[128];
    const int x = threadIdx.x;
    const float diag = aggr[x * 128 + x];
    float mrow = 0.f, mcol = 0.f;
    for (int y = 0; y < 128; ++y) {
        if (y == x) continue;
        float a_xy = aggr[x * 128 + y];
        float a_yx = aggr[y * 128 + x];
        mrow = fmaxf(mrow, 0.2f + a_xy - diag);
        mcol = fmaxf(mcol, 0.2f + a_yx - diag);
    }
    red[x] = mrow + mcol;
    __syncthreads();
    if (x == 0) {
        float s = 0.f;
        for (int i = 0; i < 128; ++i) s += red[i];
        *out = s;
    }
}

// ---------------------------------------------------------------------------
extern "C" void kernel_launch(void* const* d_in, const int* in_sizes, int n_in,
                              void* d_out, int out_size, void* d_ws, size_t ws_size,
                              hipStream_t stream)
{
    const float* im_set = (const float*)d_in[0];
    const float* s_seq  = (const float*)d_in[1];
    const int*   im_len = (const int*)d_in[2];
    const int*   s_len  = (const int*)d_in[3];
    float* out = (float*)d_out;

    unsigned char* Abf = (unsigned char*)d_ws;                          // 8 MiB
    unsigned char* Bbf = (unsigned char*)d_ws + (8u << 20);             // 8 MiB
    float*         agg = (float*)((char*)d_ws + (16u << 20));           // 64 KiB

    conv_kernel<<<16384, 256, 0, stream>>>(im_set, im_len, s_seq, s_len, Abf, Bbf);

    gemm_aggr_kernel<<<dim3(32, 32), 512, 0, stream>>>(Abf, Bbf, agg);

    loss_kernel<<<1, 128, 0, stream>>>(agg, out);
}